// Round 11
// baseline (46.953 us; speedup 1.0000x reference)
//
#include <hip/hip_runtime.h>

// YOLO loss. B=32, H=W=32, A=9, C=80, T=50, NET=512.
// R10 compute, restructured for latency hiding: each 4-lane group owns
// 4 cells, processed with double-buffered register prefetch
// (load chunk k+1 while computing chunk k). Block = 256 threads = 64 groups
// = 256 cells. Grid = 1152 blocks (36/batch). Per-wave tables, no barriers,
// no atomics. Wave partial -> ws[4*block+wid]; stage 2 sums 144/batch.

constexpr int NT = 50;
typedef __attribute__((ext_vector_type(4))) float f4;

__global__ __launch_bounds__(256) void yolo_loss_kernel(
    const float* __restrict__ y_pred,     // (B,H,W,A,85) flat
    const float* __restrict__ y_true,     // (B,H,W,A,85)
    const float* __restrict__ true_boxes, // (B,50,4)
    const float* __restrict__ anchors,    // (9,2)
    float* __restrict__ ws)               // (4608,) wave partials
{
    __shared__ f4    s_box[4][NT];        // per-wave {minx,maxx,miny,maxy}
    __shared__ float s_area[4][NT];
    __shared__ float s_anch[4][18];

    const int tid  = threadIdx.x;
    const int lane = tid & 63;
    const int wid  = tid >> 6;
    const int s    = tid & 3;             // slice within cell group
    const int g    = tid >> 2;            // group within block: 0..63
    const int gb   = lane & ~3;           // group base lane in wave

    const int cellB = blockIdx.x * 256;   // block's first cell
    const int b     = cellB / 9216;       // 36 blocks per batch image

    // ---- chunk loader: lane s owns floats idx=4j+s of its cell ----
    auto loadC = [&](int K, float (&PV)[21], float (&TV)[21],
                     float& P84, float& T84) {
        const size_t base_ = (size_t)(cellB + K * 64 + g) * 85 + s;
        const float* P_ = y_pred + base_;
        const float* T_ = y_true + base_;
        #pragma unroll
        for (int j = 0; j < 21; ++j) PV[j] = P_[4 * j];
        #pragma unroll
        for (int j = 0; j < 21; ++j) TV[j] = T_[4 * j];
        P84 = 0.0f; T84 = 0.0f;
        if (s == 0) { P84 = P_[84]; T84 = T_[84]; }
    };

    float pvA[21], tvA[21], p84A, t84A;
    float pvB[21], tvB[21], p84B, t84B;

    // issue chunk-0 loads FIRST (overlap with table staging)
    loadC(0, pvA, tvA, p84A, t84A);

    // ---- per-wave tables (wave-local fence only) ----
    if (lane < NT) {
        f4 tb;
        __builtin_memcpy(&tb, true_boxes + ((size_t)b * NT + lane) * 4, 16);
        const float tx = tb[0] * (1.0f / 32.0f);
        const float ty = tb[1] * (1.0f / 32.0f);
        const float tw = tb[2] * (1.0f / 512.0f);
        const float th = tb[3] * (1.0f / 512.0f);
        f4 e;
        e[0] = tx - tw * 0.5f;  e[1] = tx + tw * 0.5f;
        e[2] = ty - th * 0.5f;  e[3] = ty + th * 0.5f;
        s_box[wid][lane]  = e;
        s_area[wid][lane] = tw * th;
    }
    if (lane < 18) s_anch[wid][lane] = anchors[lane];
    asm volatile("s_waitcnt lgkmcnt(0)" ::: "memory");
    __builtin_amdgcn_sched_barrier(0);

    // ---- per-cell compute (R10-verified), returns s==0-masked partial ----
    auto doCell = [&](int K, const float (&pv)[21], const float (&tv)[21],
                      float p84, float t84) -> float {
        const int cell  = cellB + K * 64 + g;
        const int local = cell - b * 9216;
        const int a = local % 9;
        const int w = (local / 9) % 32;
        const int h = local / 288;

        const float p0 = __shfl(pv[0], gb + 0);
        const float p1 = __shfl(pv[0], gb + 1);
        const float p2 = __shfl(pv[0], gb + 2);
        const float p3 = __shfl(pv[0], gb + 3);
        const float p4 = __shfl(pv[1], gb + 0);
        const float t0 = __shfl(tv[0], gb + 0);
        const float t1 = __shfl(tv[0], gb + 1);
        const float t2 = __shfl(tv[0], gb + 2);
        const float t3 = __shfl(tv[0], gb + 3);
        const float t4 = __shfl(tv[1], gb + 0);

        const float aw = s_anch[wid][a * 2 + 0];
        const float ah = s_anch[wid][a * 2 + 1];

        const float sig0  = 1.0f / (1.0f + __expf(-p0));
        const float sig1  = 1.0f / (1.0f + __expf(-p1));
        const float predx = (float)w + sig0;
        const float predy = (float)h + sig1;
        const float pconf = 1.0f / (1.0f + __expf(-p4));

        const float px = predx * (1.0f / 32.0f);
        const float py = predy * (1.0f / 32.0f);
        const float pw = __expf(p2) * aw * (1.0f / 512.0f);
        const float ph = __expf(p3) * ah * (1.0f / 512.0f);
        const float pminx = px - pw * 0.5f, pmaxx = px + pw * 0.5f;
        const float pminy = py - ph * 0.5f, pmaxy = py + ph * 0.5f;
        const float parea = pw * ph;

        // IoU ignore: best_iou >= 0.5 <=> exists t: 2*inter >= union
        int ig = 0;
        #pragma unroll
        for (int i = 0; i < 13; ++i) {
            const int box = i * 4 + s;
            if (box < NT) {
                const f4 e = s_box[wid][box];
                float iw = fminf(pmaxx, e[1]) - fmaxf(pminx, e[0]);
                float ih = fminf(pmaxy, e[3]) - fmaxf(pminy, e[2]);
                iw = fmaxf(iw, 0.0f);
                ih = fmaxf(ih, 0.0f);
                const float inter = iw * ih;
                const float uni   = parea + s_area[wid][box] - inter;
                ig |= (2.0f * inter >= uni) ? 1 : 0;
            }
        }
        ig |= __shfl_xor(ig, 1);
        ig |= __shfl_xor(ig, 2);

        // classes pass A: argmax(true) carrying pred + max(pred)
        float tmax = -1e30f, p_at = 0.0f, pmax = -1e30f;
        #pragma unroll
        for (int j = 0; j < 21; ++j) {
            const bool cls = (j >= 2) || (j == 1 && s != 0) || (4 * j + s >= 5);
            const float tcm = cls ? tv[j] : -1e30f;
            const float pcm = cls ? pv[j] : -1e30f;
            if (tcm > tmax) { tmax = tcm; p_at = pv[j]; }
            pmax = fmaxf(pmax, pcm);
        }
        {
            const float tcm = (s == 0) ? t84 : -1e30f;
            if (tcm > tmax) { tmax = tcm; p_at = p84; }
            pmax = fmaxf(pmax, (s == 0) ? p84 : -1e30f);
        }
        #pragma unroll
        for (int d = 1; d <= 2; d <<= 1) {
            const float ot = __shfl_xor(tmax, d);
            const float op = __shfl_xor(p_at, d);
            if (ot > tmax) { tmax = ot; p_at = op; }
            pmax = fmaxf(pmax, __shfl_xor(pmax, d));
        }

        // classes pass B: independent exps, 4 accumulator streams
        float acc0 = 0.f, acc1 = 0.f, acc2 = 0.f, acc3 = 0.f;
        #pragma unroll
        for (int j = 0; j < 21; ++j) {
            const bool cls = (j >= 2) || (j == 1 && s != 0) || (4 * j + s >= 5);
            const float e = __expf(pv[j] - pmax);
            const float v = cls ? e : 0.0f;
            if ((j & 3) == 0) acc0 += v;
            else if ((j & 3) == 1) acc1 += v;
            else if ((j & 3) == 2) acc2 += v;
            else acc3 += v;
        }
        {
            const float e = __expf(p84 - pmax);
            acc1 += (s == 0) ? e : 0.0f;
        }
        float sum = (acc0 + acc1) + (acc2 + acc3);
        sum += __shfl_xor(sum, 1);
        sum += __shfl_xor(sum, 2);
        const float ce = (pmax + __logf(sum)) - p_at;

        // deltas
        const float om  = t4;
        const float ew  = __expf(t2) * aw * (1.0f / 512.0f);
        const float eh  = __expf(t3) * ah * (1.0f / 512.0f);
        const float whs = 2.0f - ew * eh;

        const float xyd0 = om * (predx - t0) * whs;
        const float xyd1 = om * (predy - t1) * whs;
        const float whd0 = om * (p2 - t2) * whs;
        const float whd1 = om * (p3 - t3) * whs;
        const float cd   = om * (pconf - t4) * 5.0f +
                           (1.0f - om) * (ig ? 0.0f : pconf);

        const float partial = xyd0 * xyd0 + xyd1 * xyd1 + whd0 * whd0 +
                              whd1 * whd1 + cd * cd + om * ce;
        return (s == 0) ? partial : 0.0f;
    };

    // ---- software pipeline: load(k+1) issued before compute(k) ----
    float accp = 0.0f;
    loadC(1, pvB, tvB, p84B, t84B);
    accp += doCell(0, pvA, tvA, p84A, t84A);
    loadC(2, pvA, tvA, p84A, t84A);
    accp += doCell(1, pvB, tvB, p84B, t84B);
    loadC(3, pvB, tvB, p84B, t84B);
    accp += doCell(2, pvA, tvA, p84A, t84A);
    accp += doCell(3, pvB, tvB, p84B, t84B);

    // ---- single wave reduction at the end (partials pre-masked) ----
    #pragma unroll
    for (int off = 32; off > 0; off >>= 1)
        accp += __shfl_down(accp, off);
    if (lane == 0)
        ws[blockIdx.x * 4 + wid] = accp;
}

// Stage 2: one wave per batch sums its 144 wave-partials.
__global__ __launch_bounds__(64) void yolo_reduce_kernel(
    const float* __restrict__ ws,   // (4608,) = (32, 144)
    float* __restrict__ out)        // (B,)
{
    const int b    = blockIdx.x;
    const int lane = threadIdx.x;
    const float* p = ws + b * 144;

    float v = p[lane] + p[lane + 64] + ((lane < 16) ? p[lane + 128] : 0.0f);
    #pragma unroll
    for (int off = 32; off > 0; off >>= 1)
        v += __shfl_down(v, off);
    if (lane == 0) out[b] = v;
}

extern "C" void kernel_launch(void* const* d_in, const int* in_sizes, int n_in,
                              void* d_out, int out_size, void* d_ws, size_t ws_size,
                              hipStream_t stream) {
    // setup_inputs order: input_image (unused), y_pred, y_true, true_boxes, anchors
    const float* y_pred     = (const float*)d_in[1];
    const float* y_true     = (const float*)d_in[2];
    const float* true_boxes = (const float*)d_in[3];
    const float* anchors    = (const float*)d_in[4];
    float* out = (float*)d_out;
    float* ws  = (float*)d_ws;   // 4608 floats; fully written before read

    dim3 grid(294912 / 256);     // 1152 blocks, 256 cells each
    yolo_loss_kernel<<<grid, 256, 0, stream>>>(y_pred, y_true, true_boxes, anchors, ws);
    yolo_reduce_kernel<<<32, 64, 0, stream>>>(ws, out);
}

// Round 12
// 39.038 us; speedup vs baseline: 1.2028x; 1.2028x over previous
//
#include <hip/hip_runtime.h>

// YOLO loss. B=32, H=W=32, A=9, C=80, T=50, NET=512.
// R12 = R5's dense 16B-per-lane loads (lane s owns float runs [16j+4s..+3];
// per cell+instr the 4 lanes touch 64 CONTIGUOUS bytes -> ~4x fewer L1/TA
// requests than 4B-interleaved R8/R10) + R10's verified compute (two-pass
// LSE, per-wave tables, no barriers) + atomic-free tail (R8's fix).
// Block = 256 = 64 cells (16/wave). Grid = 4608. Stage 2 sums 576/batch.

constexpr int NT = 50;
typedef __attribute__((ext_vector_type(4))) float f4;

__global__ __launch_bounds__(256) void yolo_loss_kernel(
    const float* __restrict__ y_pred,     // (B,H,W,A,85) flat
    const float* __restrict__ y_true,     // (B,H,W,A,85)
    const float* __restrict__ true_boxes, // (B,50,4)
    const float* __restrict__ anchors,    // (9,2)
    float* __restrict__ ws)               // (18432,) wave partials
{
    __shared__ f4    s_box[4][NT];        // per-wave {minx,maxx,miny,maxy}
    __shared__ float s_area[4][NT];
    __shared__ float s_anch[4][18];

    const int tid  = threadIdx.x;
    const int lane = tid & 63;
    const int wid  = tid >> 6;
    const int s    = tid & 3;             // slice within cell group
    const int g    = tid >> 2;            // cell within block: 0..63
    const int gb   = lane & ~3;           // group base lane in wave

    const int cell0 = blockIdx.x * 64;    // 64 cells per block, same batch b
    const int b     = cell0 / 9216;

    const int cell  = cell0 + g;
    const int local = cell - b * 9216;
    const int a = local % 9;
    const int w = (local / 9) % 32;
    const int h = local / 288;

    const float* cp = y_pred + (size_t)cell * 85;
    const float* ct = y_true + (size_t)cell * 85;

    // ---- dense 16-B loads: lane s owns float runs f = 16j+4s+e.
    //      Per instruction, each cell's 4 lanes cover 64 contiguous bytes.
    //      Named registers only (SROA-safe). All independent -> full MLP. ----
    f4 pA0, pA1, pA2, pA3, pA4, tA0, tA1, tA2, tA3, tA4;
    __builtin_memcpy(&pA0, cp +      4 * s, 16);
    __builtin_memcpy(&pA1, cp + 16 + 4 * s, 16);
    __builtin_memcpy(&pA2, cp + 32 + 4 * s, 16);
    __builtin_memcpy(&pA3, cp + 48 + 4 * s, 16);
    __builtin_memcpy(&pA4, cp + 64 + 4 * s, 16);
    __builtin_memcpy(&tA0, ct +      4 * s, 16);
    __builtin_memcpy(&tA1, ct + 16 + 4 * s, 16);
    __builtin_memcpy(&tA2, ct + 32 + 4 * s, 16);
    __builtin_memcpy(&tA3, ct + 48 + 4 * s, 16);
    __builtin_memcpy(&tA4, ct + 64 + 4 * s, 16);
    f4 pt = {0.f,0.f,0.f,0.f}, tt = {0.f,0.f,0.f,0.f};
    float p84 = 0.f, t84 = 0.f;
    if (s == 0) {                          // floats 80..83
        __builtin_memcpy(&pt, cp + 80, 16);
        __builtin_memcpy(&tt, ct + 80, 16);
    }
    if (s == 1) { p84 = cp[84]; t84 = ct[84]; }  // float 84

    // ---- per-wave tables (wave-local fence only; no block barrier) ----
    if (lane < NT) {
        f4 tb;
        __builtin_memcpy(&tb, true_boxes + ((size_t)b * NT + lane) * 4, 16);
        const float tx = tb[0] * (1.0f / 32.0f);
        const float ty = tb[1] * (1.0f / 32.0f);
        const float tw = tb[2] * (1.0f / 512.0f);
        const float th = tb[3] * (1.0f / 512.0f);
        f4 e;
        e[0] = tx - tw * 0.5f;  e[1] = tx + tw * 0.5f;
        e[2] = ty - th * 0.5f;  e[3] = ty + th * 0.5f;
        s_box[wid][lane]  = e;
        s_area[wid][lane] = tw * th;
    }
    if (lane < 18) s_anch[wid][lane] = anchors[lane];
    asm volatile("s_waitcnt lgkmcnt(0)" ::: "memory");  // wave-local LDS fence
    __builtin_amdgcn_sched_barrier(0);

    // ---- gather box fields: f0..f3 on lane gb (s=0) elems 0..3; f4 on
    //      lane gb+1 (s=1) elem 0 ----
    const float p0 = __shfl(pA0[0], gb + 0);
    const float p1 = __shfl(pA0[1], gb + 0);
    const float p2 = __shfl(pA0[2], gb + 0);
    const float p3 = __shfl(pA0[3], gb + 0);
    const float p4 = __shfl(pA0[0], gb + 1);
    const float t0 = __shfl(tA0[0], gb + 0);
    const float t1 = __shfl(tA0[1], gb + 0);
    const float t2 = __shfl(tA0[2], gb + 0);
    const float t3 = __shfl(tA0[3], gb + 0);
    const float t4 = __shfl(tA0[0], gb + 1);

    const float aw = s_anch[wid][a * 2 + 0];
    const float ah = s_anch[wid][a * 2 + 1];

    // ---- geometry (redundant on 4 lanes — cheap) ----
    const float sig0  = 1.0f / (1.0f + __expf(-p0));
    const float sig1  = 1.0f / (1.0f + __expf(-p1));
    const float predx = (float)w + sig0;
    const float predy = (float)h + sig1;
    const float pconf = 1.0f / (1.0f + __expf(-p4));

    const float px = predx * (1.0f / 32.0f);
    const float py = predy * (1.0f / 32.0f);
    const float pw = __expf(p2) * aw * (1.0f / 512.0f);
    const float ph = __expf(p3) * ah * (1.0f / 512.0f);
    const float pminx = px - pw * 0.5f, pmaxx = px + pw * 0.5f;
    const float pminy = py - ph * 0.5f, pmaxy = py + ph * 0.5f;
    const float parea = pw * ph;

    // ---- IoU ignore flag: 12-13 boxes per lane; OR across group ----
    // best_iou >= 0.5  <=>  exists t: 2*inter >= union (union > 0 always)
    int ig = 0;
    #pragma unroll
    for (int i = 0; i < 13; ++i) {
        const int box = i * 4 + s;
        if (box < NT) {
            const f4 e = s_box[wid][box];
            float iw = fminf(pmaxx, e[1]) - fmaxf(pminx, e[0]);
            float ih = fminf(pmaxy, e[3]) - fmaxf(pminy, e[2]);
            iw = fmaxf(iw, 0.0f);
            ih = fmaxf(ih, 0.0f);
            const float inter = iw * ih;
            const float uni   = parea + s_area[wid][box] - inter;
            ig |= (2.0f * inter >= uni) ? 1 : 0;
        }
    }
    ig |= __shfl_xor(ig, 1);
    ig |= __shfl_xor(ig, 2);

    // ---- classes pass A: argmax(true) carrying pred + max(pred).
    //      cls = (f = 16j+4s+e >= 5): compile-time for j>=1; j==0 -> 4s+e>=5. ----
    float tmax = -1e30f, p_at = 0.0f, pmax = -1e30f;
#define STEPA(PV, TV, J, E) {                                              \
        const bool cls = ((J) > 0) || (4 * s + (E) >= 5);                  \
        const float tcm = cls ? (TV)[(E)] : -1e30f;                        \
        const float pcm = cls ? (PV)[(E)] : -1e30f;                        \
        if (tcm > tmax) { tmax = tcm; p_at = (PV)[(E)]; }                  \
        pmax = fmaxf(pmax, pcm); }
#define SLICEA(PV, TV, J) STEPA(PV,TV,J,0) STEPA(PV,TV,J,1) STEPA(PV,TV,J,2) STEPA(PV,TV,J,3)
    SLICEA(pA0, tA0, 0) SLICEA(pA1, tA1, 1) SLICEA(pA2, tA2, 2)
    SLICEA(pA3, tA3, 3) SLICEA(pA4, tA4, 4)
#define TAILA(E) {                                                         \
        const float tcm = (s == 0) ? tt[(E)] : -1e30f;                     \
        if (tcm > tmax) { tmax = tcm; p_at = pt[(E)]; }                    \
        pmax = fmaxf(pmax, (s == 0) ? pt[(E)] : -1e30f); }
    TAILA(0) TAILA(1) TAILA(2) TAILA(3)
    {
        const float tcm = (s == 1) ? t84 : -1e30f;
        if (tcm > tmax) { tmax = tcm; p_at = p84; }
        pmax = fmaxf(pmax, (s == 1) ? p84 : -1e30f);
    }
    // combine across the 4 lanes of the group
    #pragma unroll
    for (int d = 1; d <= 2; d <<= 1) {
        const float ot = __shfl_xor(tmax, d);
        const float op = __shfl_xor(p_at, d);
        if (ot > tmax) { tmax = ot; p_at = op; }
        pmax = fmaxf(pmax, __shfl_xor(pmax, d));
    }

    // ---- classes pass B: independent exps, 4 accumulator streams ----
    float ac0 = 0.f, ac1 = 0.f, ac2 = 0.f, ac3 = 0.f;
#define STEPB(PV, J, E, AC) {                                              \
        const bool cls = ((J) > 0) || (4 * s + (E) >= 5);                  \
        const float e_ = __expf((PV)[(E)] - pmax);                         \
        AC += cls ? e_ : 0.0f; }
#define SLICEB(PV, J) STEPB(PV,J,0,ac0) STEPB(PV,J,1,ac1) STEPB(PV,J,2,ac2) STEPB(PV,J,3,ac3)
    SLICEB(pA0, 0) SLICEB(pA1, 1) SLICEB(pA2, 2) SLICEB(pA3, 3) SLICEB(pA4, 4)
    {
        const float e0 = __expf(pt[0] - pmax);
        const float e1 = __expf(pt[1] - pmax);
        const float e2 = __expf(pt[2] - pmax);
        const float e3 = __expf(pt[3] - pmax);
        ac0 += (s == 0) ? e0 : 0.0f;
        ac1 += (s == 0) ? e1 : 0.0f;
        ac2 += (s == 0) ? e2 : 0.0f;
        ac3 += (s == 0) ? e3 : 0.0f;
        const float e4 = __expf(p84 - pmax);
        ac0 += (s == 1) ? e4 : 0.0f;
    }
    float sum = (ac0 + ac1) + (ac2 + ac3);
    sum += __shfl_xor(sum, 1);
    sum += __shfl_xor(sum, 2);
    const float ce = (pmax + __logf(sum)) - p_at;

    // ---- deltas (lane s==0 holds the cell's partial) ----
    const float om  = t4;
    const float ew  = __expf(t2) * aw * (1.0f / 512.0f);
    const float eh  = __expf(t3) * ah * (1.0f / 512.0f);
    const float whs = 2.0f - ew * eh;

    const float xyd0 = om * (predx - t0) * whs;
    const float xyd1 = om * (predy - t1) * whs;
    const float whd0 = om * (p2 - t2) * whs;
    const float whd1 = om * (p3 - t3) * whs;
    const float cd   = om * (pconf - t4) * 5.0f + (1.0f - om) * (ig ? 0.0f : pconf);

    float partial = xyd0 * xyd0 + xyd1 * xyd1 + whd0 * whd0 + whd1 * whd1 +
                    cd * cd + om * ce;
    partial = (s == 0) ? partial : 0.0f;

    // ---- wave reduction, plain store (no atomic, no barrier) ----
    #pragma unroll
    for (int off = 32; off > 0; off >>= 1)
        partial += __shfl_down(partial, off);
    if (lane == 0)
        ws[blockIdx.x * 4 + wid] = partial;
}

// Stage 2: one wave per batch sums its 576 wave-partials.
__global__ __launch_bounds__(64) void yolo_reduce_kernel(
    const float* __restrict__ ws,   // (18432,) = (32, 576)
    float* __restrict__ out)        // (B,)
{
    const int b    = blockIdx.x;
    const int lane = threadIdx.x;
    const float* p = ws + b * 576;

    float v = 0.0f;
    #pragma unroll
    for (int k = 0; k < 9; ++k) v += p[lane + 64 * k];
    #pragma unroll
    for (int off = 32; off > 0; off >>= 1)
        v += __shfl_down(v, off);
    if (lane == 0) out[b] = v;
}

extern "C" void kernel_launch(void* const* d_in, const int* in_sizes, int n_in,
                              void* d_out, int out_size, void* d_ws, size_t ws_size,
                              hipStream_t stream) {
    // setup_inputs order: input_image (unused), y_pred, y_true, true_boxes, anchors
    const float* y_pred     = (const float*)d_in[1];
    const float* y_true     = (const float*)d_in[2];
    const float* true_boxes = (const float*)d_in[3];
    const float* anchors    = (const float*)d_in[4];
    float* out = (float*)d_out;
    float* ws  = (float*)d_ws;   // 18432 floats; fully written before read

    dim3 grid(294912 / 64);      // 4608 blocks, 64 cells each
    yolo_loss_kernel<<<grid, 256, 0, stream>>>(y_pred, y_true, true_boxes, anchors, ws);
    yolo_reduce_kernel<<<32, 64, 0, stream>>>(ws, out);
}